// Round 1
// baseline (13332.928 us; speedup 1.0000x reference)
//
#include <hip/hip_runtime.h>
#include <hip/hip_bf16.h>
#include <cstdint>
#include <cstddef>

typedef __attribute__((ext_vector_type(8))) short bf16x8;
typedef __attribute__((ext_vector_type(4))) float f32x4;

#define DEV static __device__ __forceinline__

DEV float bf2f(uint16_t u){ union{uint32_t i; float f;} c; c.i = ((uint32_t)u) << 16; return c.f; }
DEV uint16_t f2bf(float f){ union{float f; uint32_t i;} c; c.f = f; uint32_t r = c.i + 0x7FFFu + ((c.i >> 16) & 1u); return (uint16_t)(r >> 16); }

DEV f32x4 mfma16(bf16x8 a, bf16x8 b, f32x4 c){
  return __builtin_amdgcn_mfma_f32_16x16x32_bf16(a, b, c, 0, 0, 0);
}

// ---------------------------------------------------------------------------
// Gate MLP: c[s] = mean_b sigmoid( silu(x[b,s,:]@W1^T + b1) @ W2^T + b2 )
// grid (1024, 3), block 128 = 8 b x 16 ch
// ---------------------------------------------------------------------------
__global__ __launch_bounds__(128) void nltm_coeff(
    const float* __restrict__ x,
    const float* __restrict__ aW1, const float* __restrict__ ab1,
    const float* __restrict__ aW2, const float* __restrict__ ab2,
    const float* __restrict__ tW1, const float* __restrict__ tb1,
    const float* __restrict__ tW2, const float* __restrict__ tb2,
    const float* __restrict__ eW1, const float* __restrict__ eb1,
    const float* __restrict__ eW2, const float* __restrict__ eb2,
    float* __restrict__ gates)
{
  const int s = blockIdx.x, z = blockIdx.y;
  const int b = threadIdx.x >> 4, ch = threadIdx.x & 15;
  const float* w1 = (z==0)?aW1:(z==1)?tW1:eW1;
  const float* c1 = (z==0)?ab1:(z==1)?tb1:eb1;
  const float* w2 = (z==0)?aW2:(z==1)?tW2:eW2;
  const float* c2 = (z==0)?ab2:(z==1)?tb2:eb2;
  const float4* xp = (const float4*)(x + ((size_t)(b << 10) + s)*512);
  const float4* wp = (const float4*)(w1 + ch*512);
  float dot = 0.f;
  #pragma unroll 4
  for (int i = 0; i < 128; ++i){
    float4 a = xp[i], c = wp[i];
    dot += a.x*c.x + a.y*c.y + a.z*c.z + a.w*c.w;
  }
  dot += c1[ch];
  const float sg = 1.f / (1.f + __expf(-dot));
  float v = dot * sg * w2[ch];
  v += __shfl_xor(v, 1, 64);
  v += __shfl_xor(v, 2, 64);
  v += __shfl_xor(v, 4, 64);
  v += __shfl_xor(v, 8, 64);
  if (ch == 0){
    const float cc = 1.f / (1.f + __expf(-(v + c2[0])));
    atomicAdd(gates + (z << 10) + s, cc * 0.125f);
  }
}

// ---------------------------------------------------------------------------
// f32 GEMM: pre[n,m] = sum_d x[n,d]*W[m,d]  (NT), bf16 output
// grid (64, 4, 3), block 256; 128x128 tile, BK=16, 8x8 micro
// ---------------------------------------------------------------------------
__global__ __launch_bounds__(256) void nltm_gemm(
    const float* __restrict__ x, const float* __restrict__ Wk,
    const float* __restrict__ Wv, const float* __restrict__ Wq,
    uint16_t* __restrict__ preK, uint16_t* __restrict__ preV, uint16_t* __restrict__ preQ)
{
  __shared__ float As[16][132];
  __shared__ float Bs[16][132];
  const float* W = (blockIdx.z == 0) ? Wk : (blockIdx.z == 1) ? Wv : Wq;
  uint16_t* op  = (blockIdx.z == 0) ? preK : (blockIdx.z == 1) ? preV : preQ;
  const int tid = threadIdx.x;
  const int n0 = blockIdx.x << 7, m0 = blockIdx.y << 7;
  const int r = tid >> 1, cs = (tid & 1) << 3;
  const int ty = tid >> 4, tx = tid & 15;
  float acc[8][8];
  #pragma unroll
  for (int i = 0; i < 8; ++i)
    #pragma unroll
    for (int j = 0; j < 8; ++j) acc[i][j] = 0.f;

  for (int k0 = 0; k0 < 512; k0 += 16){
    float4 a0 = *(const float4*)(x + (size_t)(n0 + r)*512 + k0 + cs);
    float4 a1 = *(const float4*)(x + (size_t)(n0 + r)*512 + k0 + cs + 4);
    float4 b0 = *(const float4*)(W + (size_t)(m0 + r)*512 + k0 + cs);
    float4 b1 = *(const float4*)(W + (size_t)(m0 + r)*512 + k0 + cs + 4);
    __syncthreads();
    As[cs+0][r]=a0.x; As[cs+1][r]=a0.y; As[cs+2][r]=a0.z; As[cs+3][r]=a0.w;
    As[cs+4][r]=a1.x; As[cs+5][r]=a1.y; As[cs+6][r]=a1.z; As[cs+7][r]=a1.w;
    Bs[cs+0][r]=b0.x; Bs[cs+1][r]=b0.y; Bs[cs+2][r]=b0.z; Bs[cs+3][r]=b0.w;
    Bs[cs+4][r]=b1.x; Bs[cs+5][r]=b1.y; Bs[cs+6][r]=b1.z; Bs[cs+7][r]=b1.w;
    __syncthreads();
    #pragma unroll
    for (int kk = 0; kk < 16; ++kk){
      float4 av0 = *(const float4*)&As[kk][ty*8];
      float4 av1 = *(const float4*)&As[kk][ty*8+4];
      float4 bv0 = *(const float4*)&Bs[kk][tx*8];
      float4 bv1 = *(const float4*)&Bs[kk][tx*8+4];
      const float aa[8] = {av0.x,av0.y,av0.z,av0.w,av1.x,av1.y,av1.z,av1.w};
      const float bb[8] = {bv0.x,bv0.y,bv0.z,bv0.w,bv1.x,bv1.y,bv1.z,bv1.w};
      #pragma unroll
      for (int i = 0; i < 8; ++i)
        #pragma unroll
        for (int j = 0; j < 8; ++j)
          acc[i][j] = fmaf(aa[i], bb[j], acc[i][j]);
    }
  }
  #pragma unroll
  for (int i = 0; i < 8; ++i){
    const size_t n = (size_t)(n0 + ty*8 + i);
    uint4 v;
    v.x = (uint32_t)f2bf(acc[i][0]) | ((uint32_t)f2bf(acc[i][1]) << 16);
    v.y = (uint32_t)f2bf(acc[i][2]) | ((uint32_t)f2bf(acc[i][3]) << 16);
    v.z = (uint32_t)f2bf(acc[i][4]) | ((uint32_t)f2bf(acc[i][5]) << 16);
    v.w = (uint32_t)f2bf(acc[i][6]) | ((uint32_t)f2bf(acc[i][7]) << 16);
    *(uint4*)(op + n*512 + m0 + tx*8) = v;
  }
}

// ---------------------------------------------------------------------------
// depthwise conv (K=3, same) + optional LN; post layout [S][B][M] bf16
// grid (8192, 3), block 512
// ---------------------------------------------------------------------------
__global__ __launch_bounds__(512) void nltm_conv(
    const uint16_t* __restrict__ preK, const uint16_t* __restrict__ preV, const uint16_t* __restrict__ preQ,
    const float* __restrict__ ckw, const float* __restrict__ ckb,
    const float* __restrict__ cvw, const float* __restrict__ cvb,
    const float* __restrict__ cqw, const float* __restrict__ cqb,
    const float* __restrict__ lng, const float* __restrict__ lnb,
    uint16_t* __restrict__ postK, uint16_t* __restrict__ postV, uint16_t* __restrict__ postQ)
{
  const int z = blockIdx.y;
  const int b = blockIdx.x >> 10, s = blockIdx.x & 1023;
  const int m = threadIdx.x;
  const uint16_t* pre = (z==0)?preK:(z==1)?preV:preQ;
  const float* w  = (z==0)?ckw:(z==1)?cvw:cqw;
  const float* wb = (z==0)?ckb:(z==1)?cvb:cqb;
  uint16_t* post = (z==0)?postK:(z==1)?postV:postQ;
  const size_t base = ((size_t)(b << 10) + s)*512 + m;
  const float xm = (s > 0)    ? bf2f(pre[base - 512]) : 0.f;
  const float x0 = bf2f(pre[base]);
  const float xp = (s < 1023) ? bf2f(pre[base + 512]) : 0.f;
  float y = fmaf(w[m*3], xm, fmaf(w[m*3+1], x0, fmaf(w[m*3+2], xp, wb[m])));
  if (z != 1){
    __shared__ float red[2][8];
    float s1 = y, s2 = y*y;
    #pragma unroll
    for (int o = 32; o > 0; o >>= 1){
      s1 += __shfl_xor(s1, o, 64);
      s2 += __shfl_xor(s2, o, 64);
    }
    if ((threadIdx.x & 63) == 0){ red[0][threadIdx.x>>6] = s1; red[1][threadIdx.x>>6] = s2; }
    __syncthreads();
    float t1 = 0.f, t2 = 0.f;
    #pragma unroll
    for (int i = 0; i < 8; ++i){ t1 += red[0][i]; t2 += red[1][i]; }
    const float mean = t1 * (1.f/512.f);
    const float var  = t2 * (1.f/512.f) - mean*mean;
    y = (y - mean) * rsqrtf(var + 1e-5f) * lng[m] + lnb[m];
  }
  post[((size_t)(s << 3) + b)*512 + m] = f2bf(y);
}

// ---------------------------------------------------------------------------
// Sequential scan: 1 block, 512 threads (8 waves), persistent over 1024 steps.
// MFMA bf16 16x16x32 everywhere; f32 master weights + momentum in registers.
// LDS map (bytes):
//  W1L [32][520] bf16 @0 (33280)       | W2L [512][32] bf16 swz @33280 (32768)
//  QL/KL/VL [16][512] bf16 swz @66048/82432/98816 (rows 8-15 = zeros forever;
//     QL bytes 0-8191 reused as phase-C scratch; KL rows 0-7 reused as
//     g_out-natural during B..C, restaged in D)
//  KT  [512][16] bf16 @115200          | GOT [512][16] bf16 (g_out^T) @131584
//  HQS/HKS [16][36] @147968/149120     | HKST [32][16] @150272
//  GSIL [16][33] @151296               | GPT [32][16] @152352
//  b1 f32 @153376, b2 f32 @153504; total 155552 <= 163840
// qkv swizzle: elem(b,m) -> b*1024 + (((m>>3)^(b&7))<<4) + (m&7)*2
// W2 swizzle:  elem(m,h) -> m*64 + (((h>>3)^(m&3))<<4) + (h&7)*2
// ---------------------------------------------------------------------------
__global__ __launch_bounds__(512, 2) void nltm_scan(
    const float* __restrict__ W1g, const float* __restrict__ b1g,
    const float* __restrict__ W2g, const float* __restrict__ b2g,
    const float* __restrict__ gates,
    const uint16_t* __restrict__ kq, const uint16_t* __restrict__ vq,
    const uint16_t* __restrict__ qq, float* __restrict__ out)
{
  constexpr uint32_t W1Lo = 0, W2Lo = 33280, QLo = 66048, KLo = 82432, VLo = 98816,
                     KTo = 115200, GOTo = 131584, HQSo = 147968, HKSo = 149120,
                     HKSTo = 150272, GSILo = 151296, GPTo = 152352, B1Lo = 153376, B2Lo = 153504;
  __shared__ __align__(16) char smem[155552];
  const int tid = threadIdx.x;
  const int lane = tid & 63;
  const int wid = tid >> 6;
  const int rb = lane & 15;
  const int kg = lane >> 4;

  float* b1L = (float*)(smem + B1Lo);
  float* b2L = (float*)(smem + B2Lo);

  // ---- master state (f32, registers) ----
  float w1m[8][4], sm1[8][4], w2m[8][4], sm2[8][4];
  #pragma unroll
  for (int i = 0; i < 8; ++i){
    const int ht = i & 1;
    const int mt = (wid << 2) + (i >> 1);
    #pragma unroll
    for (int j = 0; j < 4; ++j){
      w1m[i][j] = W1g[(ht*16 + kg*4 + j)*512 + mt*16 + rb];
      sm1[i][j] = 0.f;
      w2m[i][j] = W2g[(mt*16 + kg*4 + j)*32 + ht*16 + rb];
      sm2[i][j] = 0.f;
    }
  }
  float b2m = b2g[tid];
  float smb2 = 0.f;
  float b1m = (tid < 32) ? b1g[tid] : 0.f;
  float smb1 = 0.f;

  // ---- LDS init ----
  for (int idx = tid; idx < 16384; idx += 512){
    int h = idx >> 9, m = idx & 511;
    *(uint16_t*)(smem + W1Lo + h*1040 + m*2) = f2bf(W1g[idx]);
  }
  for (int idx = tid; idx < 16384; idx += 512){
    int m = idx >> 5, h = idx & 31;
    *(uint16_t*)(smem + W2Lo + m*64 + (((h>>3) ^ (m&3)) << 4) + ((h&7)<<1)) = f2bf(W2g[idx]);
  }
  if (tid < 32) b1L[tid] = b1g[tid];
  b2L[tid] = b2g[tid];
  for (int i = tid; i < 12288; i += 512) ((uint32_t*)(smem + QLo))[i] = 0u;
  __syncthreads();
  // stage step 0
  #pragma unroll
  for (int i = 0; i < 6; ++i){
    const int tau = i >> 1;
    const int g = ((i & 1) << 9) + tid;
    const int b = g >> 7, m4 = (g & 127) << 2;
    const uint16_t* src = (tau == 0) ? kq : (tau == 1) ? vq : qq;
    uint2 v = *(const uint2*)(src + b*512 + m4);
    *(uint2*)(smem + ((tau==0)?KLo:(tau==1)?VLo:QLo) + b*1024 + (((m4>>3) ^ (b&7))<<4) + ((m4&7)<<1)) = v;
  }
  __syncthreads();

  const f32x4 cz = {0.f, 0.f, 0.f, 0.f};

  for (int t = 0; t < 1024; ++t){
    // ---- prefetch next step's k/v/q into registers ----
    const int tn = (t < 1023) ? (t + 1) : 1023;
    uint2 pf[6];
    #pragma unroll
    for (int i = 0; i < 6; ++i){
      const int tau = i >> 1;
      const int g = ((i & 1) << 9) + tid;
      const int b = g >> 7, m4 = (g & 127) << 2;
      const uint16_t* src = (tau == 0) ? kq : (tau == 1) ? vq : qq;
      pf[i] = *(const uint2*)(src + tn*4096 + b*512 + m4);
    }
    const float a_t = gates[t], th_t = gates[1024 + t], e_t = gates[2048 + t];
    const float oma = 1.f - a_t;

    // ============ phase A: HQ = q@W1^T, HK = k@W1^T (+silu/silu'); kT build ============
    if (wid < 4){
      const int mm = wid >> 1, ht = wid & 1;
      const uint32_t srcO = mm ? KLo : QLo;
      f32x4 acc = cz;
      #pragma unroll
      for (int k0 = 0; k0 < 16; ++k0){
        const int ch = (k0 << 2) + kg;
        bf16x8 av = *(const bf16x8*)(smem + srcO + rb*1024 + ((ch ^ (rb & 7)) << 4));
        bf16x8 bv = *(const bf16x8*)(smem + W1Lo + (ht*16 + rb)*1040 + ((k0*32 + kg*8) << 1));
        acc = mfma16(av, bv, acc);
      }
      const int hh = ht*16 + rb;
      const float b1v = b1L[hh];
      #pragma unroll
      for (int j = 0; j < 4; ++j){
        const int bb = kg*4 + j;
        const float z = acc[j] + b1v;
        const float sg = 1.f / (1.f + __expf(-z));
        const float hs = z * sg;
        if (mm == 0){
          *(uint16_t*)(smem + HQSo + (bb*36 + hh)*2) = f2bf(hs);
        } else {
          const uint16_t hb = f2bf(hs);
          *(uint16_t*)(smem + HKSo + (bb*36 + hh)*2) = hb;
          *(uint16_t*)(smem + HKSTo + hh*32 + bb*2) = hb;
          *(uint16_t*)(smem + GSILo + (bb*33 + hh)*2) = f2bf(sg*(1.f + z*(1.f - sg)));
        }
      }
    } else {
      const int t4 = tid - 256;
      #pragma unroll
      for (int ii = 0; ii < 4; ++ii){
        const int cid = (t4 << 2) + ii;
        const int b = cid >> 6, c = cid & 63;
        uint4 v = *(const uint4*)(smem + KLo + b*1024 + ((c ^ (b & 7)) << 4));
        const uint32_t base = KTo + c*256 + b*2;
        *(uint16_t*)(smem + base)       = (uint16_t)v.x;
        *(uint16_t*)(smem + base + 32)  = (uint16_t)(v.x >> 16);
        *(uint16_t*)(smem + base + 64)  = (uint16_t)v.y;
        *(uint16_t*)(smem + base + 96)  = (uint16_t)(v.y >> 16);
        *(uint16_t*)(smem + base + 128) = (uint16_t)v.z;
        *(uint16_t*)(smem + base + 160) = (uint16_t)(v.z >> 16);
        *(uint16_t*)(smem + base + 192) = (uint16_t)v.w;
        *(uint16_t*)(smem + base + 224) = (uint16_t)(v.w >> 16);
      }
    }
    __syncthreads();

    // ============ phase B: y (global store) and g_out ============
    {
      uint2 h0 = *(const uint2*)(smem + HQSo + rb*72 + kg*16);
      uint2 h1 = *(const uint2*)(smem + HQSo + rb*72 + kg*16 + 8);
      uint2 e0 = *(const uint2*)(smem + HKSo + rb*72 + kg*16);
      uint2 e1 = *(const uint2*)(smem + HKSo + rb*72 + kg*16 + 8);
      bf16x8 aq, ak;
      aq[0]=(short)h0.x; aq[1]=(short)(h0.x>>16); aq[2]=(short)h0.y; aq[3]=(short)(h0.y>>16);
      aq[4]=(short)h1.x; aq[5]=(short)(h1.x>>16); aq[6]=(short)h1.y; aq[7]=(short)(h1.y>>16);
      ak[0]=(short)e0.x; ak[1]=(short)(e0.x>>16); ak[2]=(short)e0.y; ak[3]=(short)(e0.y>>16);
      ak[4]=(short)e1.x; ak[5]=(short)(e1.x>>16); ak[6]=(short)e1.y; ak[7]=(short)(e1.y>>16);
      #pragma unroll
      for (int i = 0; i < 4; ++i){
        const int mcol = (((wid << 2) + i) << 4) + rb;
        bf16x8 bw = *(const bf16x8*)(smem + W2Lo + mcol*64 + ((kg ^ (mcol & 3)) << 4));
        f32x4 cy = mfma16(aq, bw, cz);
        f32x4 ck = mfma16(ak, bw, cz);
        const float b2v = b2L[mcol];
        #pragma unroll
        for (int j = 0; j < 4; ++j){
          const int bb = kg*4 + j;
          if (bb < 8){
            out[(((size_t)bb << 10) + t)*512 + mcol] = cy[j] + b2v;
            const float vv = bf2f(*(const uint16_t*)(smem + VLo + bb*1024 + (((mcol>>3) ^ (bb&7))<<4) + ((mcol&7)<<1)));
            const float gv = (ck[j] + b2v - vv) * (2.f/4096.f);
            const uint16_t gb = f2bf(gv);
            *(uint16_t*)(smem + GOTo + mcol*32 + bb*2) = gb;
            *(uint16_t*)(smem + KLo + bb*1024 + (((mcol>>3) ^ (bb&7))<<4) + ((mcol&7)<<1)) = gb;  // g_out natural
          } else {
            *(uint16_t*)(smem + GOTo + mcol*32 + bb*2) = 0;
          }
        }
      }
    }
    __syncthreads();

    // ============ phase C: GHK = g_out @ W2 (k-split x4) ============
    {
      const int ht = wid & 1, ks = wid >> 1;
      const int hcol = ht*16 + rb;
      f32x4 acc = cz;
      #pragma unroll
      for (int kk = 0; kk < 4; ++kk){
        const int mb = ks*128 + kk*32 + kg*8;
        bf16x8 av = *(const bf16x8*)(smem + KLo + rb*1024 + ((((mb>>3)) ^ (rb&7))<<4));
        bf16x8 bv;
        #pragma unroll
        for (int e2 = 0; e2 < 8; ++e2){
          const int mi = mb + e2;
          bv[e2] = (short)*(const uint16_t*)(smem + W2Lo + mi*64 + ((((hcol>>3)) ^ (mi&3))<<4) + ((hcol&7)<<1));
        }
        acc = mfma16(av, bv, acc);
      }
      *(f32x4*)(smem + QLo + ((((ht<<2) + ks) << 8) + lane*4)*4) = acc;
    }
    __syncthreads();

    // ============ phase C2: reduce + silu' -> gpre^T ============
    {
      const int ht2 = tid >> 8, e = tid & 255;
      float sum = 0.f;
      #pragma unroll
      for (int ks2 = 0; ks2 < 4; ++ks2)
        sum += *(const float*)(smem + QLo + ((((ht2<<2) + ks2) << 8) + e)*4);
      const int l2 = e >> 2, j2 = e & 3;
      const int bb = ((l2 >> 4) << 2) + j2;
      const int hh = (ht2 << 4) + (l2 & 15);
      const float gp = sum * bf2f(*(const uint16_t*)(smem + GSILo + (bb*33 + hh)*2));
      *(uint16_t*)(smem + GPTo + hh*32 + bb*2) = f2bf(gp);
    }
    __syncthreads();

    // ============ phase D: grads (outer products), updates, restage ============
    {
      {
        uint4 gv = *(const uint4*)(smem + GOTo + tid*32);
        float gb2 = bf2f((uint16_t)gv.x) + bf2f((uint16_t)(gv.x>>16))
                  + bf2f((uint16_t)gv.y) + bf2f((uint16_t)(gv.y>>16))
                  + bf2f((uint16_t)gv.z) + bf2f((uint16_t)(gv.z>>16))
                  + bf2f((uint16_t)gv.w) + bf2f((uint16_t)(gv.w>>16));
        smb2 = e_t*smb2 - th_t*gb2;
        b2m = oma*b2m + smb2;
        b2L[tid] = b2m;
      }
      if (tid < 32){
        uint4 gv = *(const uint4*)(smem + GPTo + tid*32);
        float gb1 = bf2f((uint16_t)gv.x) + bf2f((uint16_t)(gv.x>>16))
                  + bf2f((uint16_t)gv.y) + bf2f((uint16_t)(gv.y>>16))
                  + bf2f((uint16_t)gv.z) + bf2f((uint16_t)(gv.z>>16))
                  + bf2f((uint16_t)gv.w) + bf2f((uint16_t)(gv.w>>16));
        smb1 = e_t*smb1 - th_t*gb1;
        b1m = oma*b1m + smb1;
        b1L[tid] = b1m;
      }
      bf16x8 zf;
      #pragma unroll
      for (int i = 0; i < 8; ++i) zf[i] = 0;
      // GW1[h,m] = sum_b gpre[b,h] k[b,m]
      bf16x8 ga0 = (kg < 2) ? *(const bf16x8*)(smem + GPTo + rb*32 + kg*16) : zf;
      bf16x8 ga1 = (kg < 2) ? *(const bf16x8*)(smem + GPTo + (16 + rb)*32 + kg*16) : zf;
      #pragma unroll
      for (int i = 0; i < 8; ++i){
        const int ht = i & 1;
        const int n0 = (((wid << 2)) + (i >> 1)) << 4;
        bf16x8 bv = (kg < 2) ? *(const bf16x8*)(smem + KTo + (n0 + rb)*32 + kg*16) : zf;
        f32x4 g = mfma16(ht ? ga1 : ga0, bv, cz);
        #pragma unroll
        for (int j = 0; j < 4; ++j){
          sm1[i][j] = e_t*sm1[i][j] - th_t*g[j];
          w1m[i][j] = oma*w1m[i][j] + sm1[i][j];
          *(uint16_t*)(smem + W1Lo + (ht*16 + kg*4 + j)*1040 + (n0 + rb)*2) = f2bf(w1m[i][j]);
        }
      }
      // GW2[m,h] = sum_b g_out[b,m] hk_s[b,h]
      bf16x8 gbv0 = (kg < 2) ? *(const bf16x8*)(smem + HKSTo + rb*32 + kg*16) : zf;
      bf16x8 gbv1 = (kg < 2) ? *(const bf16x8*)(smem + HKSTo + (16 + rb)*32 + kg*16) : zf;
      #pragma unroll
      for (int i = 0; i < 8; ++i){
        const int ht = i & 1;
        const int m0 = (((wid << 2)) + (i >> 1)) << 4;
        bf16x8 av = (kg < 2) ? *(const bf16x8*)(smem + GOTo + (m0 + rb)*32 + kg*16) : zf;
        f32x4 g = mfma16(av, ht ? gbv1 : gbv0, cz);
        #pragma unroll
        for (int j = 0; j < 4; ++j){
          sm2[i][j] = e_t*sm2[i][j] - th_t*g[j];
          w2m[i][j] = oma*w2m[i][j] + sm2[i][j];
          const int mrow = m0 + kg*4 + j;
          const int hcol2 = ht*16 + rb;
          *(uint16_t*)(smem + W2Lo + mrow*64 + ((((hcol2>>3)) ^ (mrow&3))<<4) + ((hcol2&7)<<1)) = f2bf(w2m[i][j]);
        }
      }
      // restage next step's k/v/q
      #pragma unroll
      for (int i = 0; i < 6; ++i){
        const int tau = i >> 1;
        const int g = ((i & 1) << 9) + tid;
        const int b = g >> 7, m4 = (g & 127) << 2;
        *(uint2*)(smem + ((tau==0)?KLo:(tau==1)?VLo:QLo) + b*1024 + (((m4>>3) ^ (b&7))<<4) + ((m4&7)<<1)) = pf[i];
      }
    }
    __syncthreads();
  }
}

// ---------------------------------------------------------------------------
extern "C" void kernel_launch(void* const* d_in, const int* in_sizes, int n_in,
                              void* d_out, int out_size, void* d_ws, size_t ws_size,
                              hipStream_t stream)
{
  const float* x   = (const float*)d_in[0];
  const float* Wk  = (const float*)d_in[1];
  const float* Wv  = (const float*)d_in[2];
  const float* Wq  = (const float*)d_in[3];
  const float* ckw = (const float*)d_in[4];
  const float* ckb = (const float*)d_in[5];
  const float* cvw = (const float*)d_in[6];
  const float* cvb = (const float*)d_in[7];
  const float* cqw = (const float*)d_in[8];
  const float* cqb = (const float*)d_in[9];
  const float* lng = (const float*)d_in[10];
  const float* lnb = (const float*)d_in[11];
  const float* W1g = (const float*)d_in[12];
  const float* b1g = (const float*)d_in[13];
  const float* W2g = (const float*)d_in[14];
  const float* b2g = (const float*)d_in[15];
  const float* aW1 = (const float*)d_in[16];
  const float* ab1 = (const float*)d_in[17];
  const float* aW2 = (const float*)d_in[18];
  const float* ab2 = (const float*)d_in[19];
  const float* tW1 = (const float*)d_in[20];
  const float* tb1 = (const float*)d_in[21];
  const float* tW2 = (const float*)d_in[22];
  const float* tb2 = (const float*)d_in[23];
  const float* eW1 = (const float*)d_in[24];
  const float* eb1 = (const float*)d_in[25];
  const float* eW2 = (const float*)d_in[26];
  const float* eb2 = (const float*)d_in[27];

  char* ws = (char*)d_ws;
  float* gates = (float*)ws;                       // 3*1024 f32
  uint16_t* preK  = (uint16_t*)(ws + 16384);       // 6 x 8MB bf16 [B][S][M] / [S][B][M]
  uint16_t* preV  = preK + 4194304;
  uint16_t* preQ  = preV + 4194304;
  uint16_t* postK = preQ + 4194304;
  uint16_t* postV = postK + 4194304;
  uint16_t* postQ = postV + 4194304;

  hipMemsetAsync(gates, 0, 3*1024*sizeof(float), stream);
  nltm_coeff<<<dim3(1024,3), 128, 0, stream>>>(x, aW1,ab1,aW2,ab2, tW1,tb1,tW2,tb2,
                                               eW1,eb1,eW2,eb2, gates);
  nltm_gemm<<<dim3(64,4,3), 256, 0, stream>>>(x, Wk, Wv, Wq, preK, preV, preQ);
  nltm_conv<<<dim3(8192,3), 512, 0, stream>>>(preK,preV,preQ, ckw,ckb,cvw,cvb,cqw,cqb,
                                              lng,lnb, postK,postV,postQ);
  nltm_scan<<<dim3(1), dim3(512), 0, stream>>>(W1g, b1g, W2g, b2g, gates,
                                               postK, postV, postQ, (float*)d_out);
}

// Round 2
// 11012.778 us; speedup vs baseline: 1.2107x; 1.2107x over previous
//
#include <hip/hip_runtime.h>
#include <hip/hip_bf16.h>
#include <cstdint>
#include <cstddef>

typedef __attribute__((ext_vector_type(8))) short bf16x8;
typedef __attribute__((ext_vector_type(4))) float f32x4;

#define DEV static __device__ __forceinline__

DEV float bf2f(uint16_t u){ union{uint32_t i; float f;} c; c.i = ((uint32_t)u) << 16; return c.f; }
DEV uint16_t f2bf(float f){ union{float f; uint32_t i;} c; c.f = f; uint32_t r = c.i + 0x7FFFu + ((c.i >> 16) & 1u); return (uint16_t)(r >> 16); }

DEV f32x4 mfma16(bf16x8 a, bf16x8 b, f32x4 c){
  return __builtin_amdgcn_mfma_f32_16x16x32_bf16(a, b, c, 0, 0, 0);
}

// ---------------------------------------------------------------------------
// Gate MLP: c[s] = mean_b sigmoid( silu(x[b,s,:]@W1^T + b1) @ W2^T + b2 )
// grid (1024, 3), block 128 = 8 b x 16 ch
// ---------------------------------------------------------------------------
__global__ __launch_bounds__(128) void nltm_coeff(
    const float* __restrict__ x,
    const float* __restrict__ aW1, const float* __restrict__ ab1,
    const float* __restrict__ aW2, const float* __restrict__ ab2,
    const float* __restrict__ tW1, const float* __restrict__ tb1,
    const float* __restrict__ tW2, const float* __restrict__ tb2,
    const float* __restrict__ eW1, const float* __restrict__ eb1,
    const float* __restrict__ eW2, const float* __restrict__ eb2,
    float* __restrict__ gates)
{
  const int s = blockIdx.x, z = blockIdx.y;
  const int b = threadIdx.x >> 4, ch = threadIdx.x & 15;
  const float* w1 = (z==0)?aW1:(z==1)?tW1:eW1;
  const float* c1 = (z==0)?ab1:(z==1)?tb1:eb1;
  const float* w2 = (z==0)?aW2:(z==1)?tW2:eW2;
  const float* c2 = (z==0)?ab2:(z==1)?tb2:eb2;
  const float4* xp = (const float4*)(x + ((size_t)(b << 10) + s)*512);
  const float4* wp = (const float4*)(w1 + ch*512);
  float dot = 0.f;
  #pragma unroll 4
  for (int i = 0; i < 128; ++i){
    float4 a = xp[i], c = wp[i];
    dot += a.x*c.x + a.y*c.y + a.z*c.z + a.w*c.w;
  }
  dot += c1[ch];
  const float sg = 1.f / (1.f + __expf(-dot));
  float v = dot * sg * w2[ch];
  v += __shfl_xor(v, 1, 64);
  v += __shfl_xor(v, 2, 64);
  v += __shfl_xor(v, 4, 64);
  v += __shfl_xor(v, 8, 64);
  if (ch == 0){
    const float cc = 1.f / (1.f + __expf(-(v + c2[0])));
    atomicAdd(gates + (z << 10) + s, cc * 0.125f);
  }
}

// ---------------------------------------------------------------------------
// f32 GEMM: pre[n,m] = sum_d x[n,d]*W[m,d]  (NT), bf16 output
// grid (64, 4, 3), block 256; 128x128 tile, BK=16, 8x8 micro
// ---------------------------------------------------------------------------
__global__ __launch_bounds__(256) void nltm_gemm(
    const float* __restrict__ x, const float* __restrict__ Wk,
    const float* __restrict__ Wv, const float* __restrict__ Wq,
    uint16_t* __restrict__ preK, uint16_t* __restrict__ preV, uint16_t* __restrict__ preQ)
{
  __shared__ float As[16][132];
  __shared__ float Bs[16][132];
  const float* W = (blockIdx.z == 0) ? Wk : (blockIdx.z == 1) ? Wv : Wq;
  uint16_t* op  = (blockIdx.z == 0) ? preK : (blockIdx.z == 1) ? preV : preQ;
  const int tid = threadIdx.x;
  const int n0 = blockIdx.x << 7, m0 = blockIdx.y << 7;
  const int r = tid >> 1, cs = (tid & 1) << 3;
  const int ty = tid >> 4, tx = tid & 15;
  float acc[8][8];
  #pragma unroll
  for (int i = 0; i < 8; ++i)
    #pragma unroll
    for (int j = 0; j < 8; ++j) acc[i][j] = 0.f;

  for (int k0 = 0; k0 < 512; k0 += 16){
    float4 a0 = *(const float4*)(x + (size_t)(n0 + r)*512 + k0 + cs);
    float4 a1 = *(const float4*)(x + (size_t)(n0 + r)*512 + k0 + cs + 4);
    float4 b0 = *(const float4*)(W + (size_t)(m0 + r)*512 + k0 + cs);
    float4 b1 = *(const float4*)(W + (size_t)(m0 + r)*512 + k0 + cs + 4);
    __syncthreads();
    As[cs+0][r]=a0.x; As[cs+1][r]=a0.y; As[cs+2][r]=a0.z; As[cs+3][r]=a0.w;
    As[cs+4][r]=a1.x; As[cs+5][r]=a1.y; As[cs+6][r]=a1.z; As[cs+7][r]=a1.w;
    Bs[cs+0][r]=b0.x; Bs[cs+1][r]=b0.y; Bs[cs+2][r]=b0.z; Bs[cs+3][r]=b0.w;
    Bs[cs+4][r]=b1.x; Bs[cs+5][r]=b1.y; Bs[cs+6][r]=b1.z; Bs[cs+7][r]=b1.w;
    __syncthreads();
    #pragma unroll
    for (int kk = 0; kk < 16; ++kk){
      float4 av0 = *(const float4*)&As[kk][ty*8];
      float4 av1 = *(const float4*)&As[kk][ty*8+4];
      float4 bv0 = *(const float4*)&Bs[kk][tx*8];
      float4 bv1 = *(const float4*)&Bs[kk][tx*8+4];
      const float aa[8] = {av0.x,av0.y,av0.z,av0.w,av1.x,av1.y,av1.z,av1.w};
      const float bb[8] = {bv0.x,bv0.y,bv0.z,bv0.w,bv1.x,bv1.y,bv1.z,bv1.w};
      #pragma unroll
      for (int i = 0; i < 8; ++i)
        #pragma unroll
        for (int j = 0; j < 8; ++j)
          acc[i][j] = fmaf(aa[i], bb[j], acc[i][j]);
    }
  }
  #pragma unroll
  for (int i = 0; i < 8; ++i){
    const size_t n = (size_t)(n0 + ty*8 + i);
    uint4 v;
    v.x = (uint32_t)f2bf(acc[i][0]) | ((uint32_t)f2bf(acc[i][1]) << 16);
    v.y = (uint32_t)f2bf(acc[i][2]) | ((uint32_t)f2bf(acc[i][3]) << 16);
    v.z = (uint32_t)f2bf(acc[i][4]) | ((uint32_t)f2bf(acc[i][5]) << 16);
    v.w = (uint32_t)f2bf(acc[i][6]) | ((uint32_t)f2bf(acc[i][7]) << 16);
    *(uint4*)(op + n*512 + m0 + tx*8) = v;
  }
}

// ---------------------------------------------------------------------------
// depthwise conv (K=3, same) + optional LN; post layout [S][B][M] bf16
// grid (8192, 3), block 512
// ---------------------------------------------------------------------------
__global__ __launch_bounds__(512) void nltm_conv(
    const uint16_t* __restrict__ preK, const uint16_t* __restrict__ preV, const uint16_t* __restrict__ preQ,
    const float* __restrict__ ckw, const float* __restrict__ ckb,
    const float* __restrict__ cvw, const float* __restrict__ cvb,
    const float* __restrict__ cqw, const float* __restrict__ cqb,
    const float* __restrict__ lng, const float* __restrict__ lnb,
    uint16_t* __restrict__ postK, uint16_t* __restrict__ postV, uint16_t* __restrict__ postQ)
{
  const int z = blockIdx.y;
  const int b = blockIdx.x >> 10, s = blockIdx.x & 1023;
  const int m = threadIdx.x;
  const uint16_t* pre = (z==0)?preK:(z==1)?preV:preQ;
  const float* w  = (z==0)?ckw:(z==1)?cvw:cqw;
  const float* wb = (z==0)?ckb:(z==1)?cvb:cqb;
  uint16_t* post = (z==0)?postK:(z==1)?postV:postQ;
  const size_t base = ((size_t)(b << 10) + s)*512 + m;
  const float xm = (s > 0)    ? bf2f(pre[base - 512]) : 0.f;
  const float x0 = bf2f(pre[base]);
  const float xp = (s < 1023) ? bf2f(pre[base + 512]) : 0.f;
  float y = fmaf(w[m*3], xm, fmaf(w[m*3+1], x0, fmaf(w[m*3+2], xp, wb[m])));
  if (z != 1){
    __shared__ float red[2][8];
    float s1 = y, s2 = y*y;
    #pragma unroll
    for (int o = 32; o > 0; o >>= 1){
      s1 += __shfl_xor(s1, o, 64);
      s2 += __shfl_xor(s2, o, 64);
    }
    if ((threadIdx.x & 63) == 0){ red[0][threadIdx.x>>6] = s1; red[1][threadIdx.x>>6] = s2; }
    __syncthreads();
    float t1 = 0.f, t2 = 0.f;
    #pragma unroll
    for (int i = 0; i < 8; ++i){ t1 += red[0][i]; t2 += red[1][i]; }
    const float mean = t1 * (1.f/512.f);
    const float var  = t2 * (1.f/512.f) - mean*mean;
    y = (y - mean) * rsqrtf(var + 1e-5f) * lng[m] + lnb[m];
  }
  post[((size_t)(s << 3) + b)*512 + m] = f2bf(y);
}

// ---------------------------------------------------------------------------
// Sequential scan: 1 block, 512 threads (8 waves), 1024 steps.
// All layouts co-designed with MFMA fragment/output mappings so every hot
// LDS access is ds_read_b128 / ds_write_b64.
// LDS map (bytes):
//  W1L  [32h][1040] bf16 @0          (33280)   read A (b128), write D (b64)
//  W2L  [512m][64] bf16 swz @33280   (32768)   read B (b128), write D (b64)
//  W2T  [32h][1040] bf16 @66048      (33280)   read C (b128), write D (b64)
//  QL/KL [8b][1024] bf16 swz @99328/@107520    q / k (then g_out natural)
//  VT   [512m][16] bf16 @115712               V^T rows (uint2 reads in B)
//  KT   [512m][16] bf16 @123904               k^T rows (b128 frags in D)
//  GOT  [512m][16] bf16 @132096               g_out^T rows
//  HQS/HKS [8b][80] bf16 @140288/@140928      hq/hk silu rows (b128 in B)
//  HKST [32h][16] @141568 | GSIT [32h][16] @142080 | GPT [32h][16] @142592
//  SCR  8*64*16 f32 @143104 (8192) | b1 @151296 | b2 @151424 ; total 153472
// ---------------------------------------------------------------------------
__global__ __launch_bounds__(512, 2) void nltm_scan(
    const float* __restrict__ W1g, const float* __restrict__ b1g,
    const float* __restrict__ W2g, const float* __restrict__ b2g,
    const float* __restrict__ gates,
    const uint16_t* __restrict__ kq, const uint16_t* __restrict__ vq,
    const uint16_t* __restrict__ qq, float* __restrict__ out)
{
  constexpr uint32_t W1Lo=0, W2Lo=33280, W2To=66048, QLo=99328, KLo=107520,
                     VTo=115712, KTo=123904, GOTo=132096, HQSo=140288, HKSo=140928,
                     HKSTo=141568, GSITo=142080, GPTo=142592, SCRo=143104,
                     B1o=151296, B2o=151424;
  __shared__ __align__(16) char smem[153472];
  const int tid = threadIdx.x;
  const int lane = tid & 63;
  const int wid = tid >> 6;
  const int rb = lane & 15;
  const int kg = lane >> 4;

  float* b1L = (float*)(smem + B1o);
  float* b2L = (float*)(smem + B2o);

  // ---- master state (f32, registers) ----
  // w1m[i=tt*2+ht][j]: W1[h=ht*16+rb][m=(wid*4+tt)*16+kg*4+j]
  // w2a[i][j]:         W2[m=(wid*4+tt)*16+kg*4+j][h=ht*16+rb]   (W2T copy)
  float w1m[8][4], sm1[8][4], w2a[8][4], sma[8][4];
  #pragma unroll
  for (int i = 0; i < 8; ++i){
    const int tt = i >> 1, ht = i & 1;
    const int mA = (wid*4 + tt)*16;
    #pragma unroll
    for (int j = 0; j < 4; ++j){
      const int h1 = ht*16 + rb, m1 = mA + kg*4 + j;
      w1m[i][j] = W1g[h1*512 + m1];  sm1[i][j] = 0.f;
      w2a[i][j] = W2g[m1*32 + h1];   sma[i][j] = 0.f;
    }
  }
  float b2m = b2g[tid], smb2 = 0.f;
  float b1m = (tid < 32) ? b1g[tid] : 0.f, smb1 = 0.f;

  // ---- LDS weights init ----
  for (int idx = tid; idx < 16384; idx += 512){
    const int h = idx >> 9, m = idx & 511;
    *(uint16_t*)(smem + W1Lo + h*1040 + m*2) = f2bf(W1g[idx]);          // idx=h*512+m
    const int m2 = idx >> 5, h2 = idx & 31;
    const float w2v = W2g[idx];                                          // idx=m2*32+h2
    *(uint16_t*)(smem + W2Lo + m2*64 + (((h2>>3)^(m2&3))<<4) + ((h2&7)<<1)) = f2bf(w2v);
    *(uint16_t*)(smem + W2To + h2*1040 + m2*2) = f2bf(w2v);
  }
  if (tid < 32) b1L[tid] = b1g[tid];
  b2L[tid] = b2g[tid];

  // ---- stage step 0 ----
  #pragma unroll
  for (int i = 0; i < 4; ++i){
    const int g = ((i & 1) << 9) + tid;
    const int b = g >> 7, m4 = (g & 127) << 2;
    const uint16_t* src = (i < 2) ? kq : qq;
    uint2 v = *(const uint2*)(src + b*512 + m4);
    *(uint2*)(smem + ((i<2)?KLo:QLo) + b*1024 + (((m4>>3)^(b&7))<<4) + ((m4&7)<<1)) = v;
  }
  {
    const uint16_t* kp = kq + tid;
    const uint16_t* vp = vq + tid;
    uint32_t a0=kp[0],a1=kp[512],a2=kp[1024],a3=kp[1536],a4=kp[2048],a5=kp[2560],a6=kp[3072],a7=kp[3584];
    uint4 kt4; kt4.x=a0|(a1<<16); kt4.y=a2|(a3<<16); kt4.z=a4|(a5<<16); kt4.w=a6|(a7<<16);
    *(uint4*)(smem + KTo + tid*16) = kt4;
    uint32_t c0=vp[0],c1=vp[512],c2=vp[1024],c3=vp[1536],c4=vp[2048],c5=vp[2560],c6=vp[3072],c7=vp[3584];
    uint4 vt4; vt4.x=c0|(c1<<16); vt4.y=c2|(c3<<16); vt4.z=c4|(c5<<16); vt4.w=c6|(c7<<16);
    *(uint4*)(smem + VTo + tid*16) = vt4;
  }
  __syncthreads();

  const f32x4 cz = {0.f, 0.f, 0.f, 0.f};
  const bf16x8 zf = {0,0,0,0,0,0,0,0};

  for (int t = 0; t < 1024; ++t){
    // ---- prefetch next step's tensors into registers ----
    const int tn = (t < 1023) ? (t + 1) : 1023;
    uint2 pf[4];
    #pragma unroll
    for (int i = 0; i < 4; ++i){
      const int g = ((i & 1) << 9) + tid;
      const int b = g >> 7, m4 = (g & 127) << 2;
      const uint16_t* src = (i < 2) ? kq : qq;
      pf[i] = *(const uint2*)(src + (size_t)tn*4096 + b*512 + m4);
    }
    uint4 ktpf, vtpf;
    {
      const uint16_t* kp = kq + (size_t)tn*4096 + tid;
      const uint16_t* vp = vq + (size_t)tn*4096 + tid;
      uint32_t a0=kp[0],a1=kp[512],a2=kp[1024],a3=kp[1536],a4=kp[2048],a5=kp[2560],a6=kp[3072],a7=kp[3584];
      ktpf.x=a0|(a1<<16); ktpf.y=a2|(a3<<16); ktpf.z=a4|(a5<<16); ktpf.w=a6|(a7<<16);
      uint32_t c0=vp[0],c1=vp[512],c2=vp[1024],c3=vp[1536],c4=vp[2048],c5=vp[2560],c6=vp[3072],c7=vp[3584];
      vtpf.x=c0|(c1<<16); vtpf.y=c2|(c3<<16); vtpf.z=c4|(c5<<16); vtpf.w=c6|(c7<<16);
    }
    const float a_t = gates[t], th_t = gates[1024 + t], e_t = gates[2048 + t];
    const float oma = 1.f - a_t;

    // ============ phase A: HQ = q@W1^T, HK = k@W1^T (+silu/silu') ============
    if (wid < 4){
      const int mm = wid >> 1, ht = wid & 1;
      const uint32_t srcO = mm ? KLo : QLo;
      const uint32_t w1row = W1Lo + (uint32_t)(ht*16 + rb)*1040;
      f32x4 acc0 = cz, acc1 = cz;
      #pragma unroll
      for (int k0 = 0; k0 < 16; k0 += 2){
        const int ch0 = (k0 << 2) + kg, ch1 = ((k0+1) << 2) + kg;
        bf16x8 a0 = (rb < 8) ? *(const bf16x8*)(smem + srcO + rb*1024 + ((ch0 ^ (rb&7)) << 4)) : zf;
        bf16x8 b0 = *(const bf16x8*)(smem + w1row + ((k0*32 + kg*8) << 1));
        acc0 = mfma16(a0, b0, acc0);
        bf16x8 a1 = (rb < 8) ? *(const bf16x8*)(smem + srcO + rb*1024 + ((ch1 ^ (rb&7)) << 4)) : zf;
        bf16x8 b1 = *(const bf16x8*)(smem + w1row + (((k0+1)*32 + kg*8) << 1));
        acc1 = mfma16(a1, b1, acc1);
      }
      f32x4 acc = acc0 + acc1;
      const int hh = ht*16 + rb;
      const float b1v = b1L[hh];
      float hsv[4], sdv[4];
      #pragma unroll
      for (int j = 0; j < 4; ++j){
        const float z = acc[j] + b1v;
        const float sg = 1.f / (1.f + __expf(-z));
        hsv[j] = z * sg;
        sdv[j] = sg * (1.f + z * (1.f - sg));
      }
      if (kg < 2){
        if (mm == 0){
          #pragma unroll
          for (int j = 0; j < 4; ++j)
            *(uint16_t*)(smem + HQSo + (kg*4+j)*80 + hh*2) = f2bf(hsv[j]);
        } else {
          #pragma unroll
          for (int j = 0; j < 4; ++j)
            *(uint16_t*)(smem + HKSo + (kg*4+j)*80 + hh*2) = f2bf(hsv[j]);
          uint2 hv; hv.x = (uint32_t)f2bf(hsv[0]) | ((uint32_t)f2bf(hsv[1])<<16);
                    hv.y = (uint32_t)f2bf(hsv[2]) | ((uint32_t)f2bf(hsv[3])<<16);
          *(uint2*)(smem + HKSTo + hh*16 + kg*8) = hv;
          uint2 sv; sv.x = (uint32_t)f2bf(sdv[0]) | ((uint32_t)f2bf(sdv[1])<<16);
                    sv.y = (uint32_t)f2bf(sdv[2]) | ((uint32_t)f2bf(sdv[3])<<16);
          *(uint2*)(smem + GSITo + hh*16 + kg*8) = sv;
        }
      }
    }
    __syncthreads();

    // ============ phase B: y (global store) and g_out ============
    {
      bf16x8 aq = (rb < 8) ? *(const bf16x8*)(smem + HQSo + rb*80 + kg*16) : zf;
      bf16x8 ak = (rb < 8) ? *(const bf16x8*)(smem + HKSo + rb*80 + kg*16) : zf;
      #pragma unroll
      for (int i = 0; i < 4; ++i){
        const int mcol = (((wid << 2) + i) << 4) + rb;
        bf16x8 bw = *(const bf16x8*)(smem + W2Lo + mcol*64 + ((kg ^ (mcol & 3)) << 4));
        f32x4 cy = mfma16(aq, bw, cz);
        f32x4 ck = mfma16(ak, bw, cz);
        const float b2v = b2L[mcol];
        if (kg < 2){
          uint2 vvp = *(const uint2*)(smem + VTo + mcol*16 + kg*8);
          const float vv0 = bf2f((uint16_t)vvp.x), vv1 = bf2f((uint16_t)(vvp.x>>16));
          const float vv2 = bf2f((uint16_t)vvp.y), vv3 = bf2f((uint16_t)(vvp.y>>16));
          float gvv[4];
          gvv[0] = (ck[0] + b2v - vv0) * (2.f/4096.f);
          gvv[1] = (ck[1] + b2v - vv1) * (2.f/4096.f);
          gvv[2] = (ck[2] + b2v - vv2) * (2.f/4096.f);
          gvv[3] = (ck[3] + b2v - vv3) * (2.f/4096.f);
          #pragma unroll
          for (int j = 0; j < 4; ++j){
            const int bb = kg*4 + j;
            out[(((size_t)bb << 10) + t)*512 + mcol] = cy[j] + b2v;
          }
          uint2 gp; gp.x = (uint32_t)f2bf(gvv[0]) | ((uint32_t)f2bf(gvv[1])<<16);
                    gp.y = (uint32_t)f2bf(gvv[2]) | ((uint32_t)f2bf(gvv[3])<<16);
          *(uint2*)(smem + GOTo + mcol*16 + kg*8) = gp;
          // g_out natural (for phase C A-fragments), reusing KL rows 0-7
          #pragma unroll
          for (int j = 0; j < 4; ++j){
            const int bb = kg*4 + j;
            *(uint16_t*)(smem + KLo + bb*1024 + (((mcol>>3) ^ (bb&7))<<4) + ((mcol&7)<<1)) = f2bf(gvv[j]);
          }
        }
      }
    }
    __syncthreads();

    // ============ phase C: GHK = g_out @ W2 (k-split x4, b128 frags) ============
    {
      const int ht = wid & 1, ks = wid >> 1;
      const int hcol = ht*16 + rb;
      f32x4 a0 = cz, a1 = cz;
      #pragma unroll
      for (int kk = 0; kk < 4; ++kk){
        const int mc8 = ks*16 + kk*4 + kg;   // m-chunk-of-8 index (0..63)
        bf16x8 av = (rb < 8) ? *(const bf16x8*)(smem + KLo + rb*1024 + ((mc8 ^ (rb&7)) << 4)) : zf;
        bf16x8 bv = *(const bf16x8*)(smem + W2To + hcol*1040 + (mc8 << 4));
        if (kk & 1) a1 = mfma16(av, bv, a1); else a0 = mfma16(av, bv, a0);
      }
      f32x4 acc = a0 + a1;
      *(f32x4*)(smem + SCRo + (((ht*4 + ks)*64 + lane) << 4)) = acc;
    }
    __syncthreads();

    // ============ phase C2: reduce + silu' -> gpre^T (waves 0-1) ============
    if (wid < 2 && kg < 2){
      const int ht = wid;
      f32x4 s = cz;
      #pragma unroll
      for (int ks = 0; ks < 4; ++ks){
        f32x4 p = *(const f32x4*)(smem + SCRo + (((ht*4 + ks)*64 + lane) << 4));
        s += p;
      }
      uint2 gs = *(const uint2*)(smem + GSITo + (ht*16 + rb)*16 + kg*8);
      const float g0 = s[0]*bf2f((uint16_t)gs.x), g1 = s[1]*bf2f((uint16_t)(gs.x>>16));
      const float g2 = s[2]*bf2f((uint16_t)gs.y), g3 = s[3]*bf2f((uint16_t)(gs.y>>16));
      uint2 w; w.x = (uint32_t)f2bf(g0) | ((uint32_t)f2bf(g1)<<16);
               w.y = (uint32_t)f2bf(g2) | ((uint32_t)f2bf(g3)<<16);
      *(uint2*)(smem + GPTo + (ht*16 + rb)*16 + kg*8) = w;
    }
    __syncthreads();

    // ============ phase D: grads, updates (packed writes), restage ============
    {
      // restage next q / k-natural first (buffers dead after A/C)
      #pragma unroll
      for (int i = 0; i < 4; ++i){
        const int g = ((i & 1) << 9) + tid;
        const int b = g >> 7, m4 = (g & 127) << 2;
        *(uint2*)(smem + ((i<2)?KLo:QLo) + b*1024 + (((m4>>3)^(b&7))<<4) + ((m4&7)<<1)) = pf[i];
      }

      bf16x8 hkF[2], gpF[2];
      #pragma unroll
      for (int ht = 0; ht < 2; ++ht){
        const int r0 = ht*16 + rb;
        hkF[ht] = (kg == 0) ? *(const bf16x8*)(smem + HKSTo + r0*16) : zf;
        gpF[ht] = (kg == 0) ? *(const bf16x8*)(smem + GPTo  + r0*16) : zf;
      }
      #pragma unroll
      for (int tt = 0; tt < 4; ++tt){
        const int mA = (wid*4 + tt)*16;
        const int r0 = mA + rb;
        bf16x8 ktf = (kg == 0) ? *(const bf16x8*)(smem + KTo  + r0*16) : zf;
        bf16x8 gof = (kg == 0) ? *(const bf16x8*)(smem + GOTo + r0*16) : zf;
        #pragma unroll
        for (int ht = 0; ht < 2; ++ht){
          const int i = tt*2 + ht;
          // GW1^T[m][h] = sum_b k[b,m] gpre[b,h] ; thread: m=mA+kg*4+j, h=ht*16+rb
          f32x4 g1 = mfma16(ktf, gpF[ht], cz);
          // GW2[m][h]  = sum_b g_out[b,m] hk[b,h]; same thread mapping
          f32x4 g2 = mfma16(gof, hkF[ht], cz);
          float f1[4], f2[4];
          #pragma unroll
          for (int j = 0; j < 4; ++j){
            sm1[i][j] = e_t*sm1[i][j] - th_t*g1[j];
            w1m[i][j] = oma*w1m[i][j] + sm1[i][j];
            f1[j] = w1m[i][j];
            sma[i][j] = e_t*sma[i][j] - th_t*g2[j];
            w2a[i][j] = oma*w2a[i][j] + sma[i][j];
            f2[j] = w2a[i][j];
          }
          uint2 u1; u1.x = (uint32_t)f2bf(f1[0]) | ((uint32_t)f2bf(f1[1])<<16);
                    u1.y = (uint32_t)f2bf(f1[2]) | ((uint32_t)f2bf(f1[3])<<16);
          *(uint2*)(smem + W1Lo + (ht*16 + rb)*1040 + (mA + kg*4)*2) = u1;
          uint2 u2; u2.x = (uint32_t)f2bf(f2[0]) | ((uint32_t)f2bf(f2[1])<<16);
                    u2.y = (uint32_t)f2bf(f2[2]) | ((uint32_t)f2bf(f2[3])<<16);
          *(uint2*)(smem + W2To + (ht*16 + rb)*1040 + (mA + kg*4)*2) = u2;
        }
      }
      // W2L ([m][h] swizzled) regenerated by transpose-readback of own-wave W2T
      // columns (bit-identical bf16, no second master set needed).
      #pragma unroll
      for (int tt = 0; tt < 4; ++tt){
        const int m2 = (wid*4 + tt)*16 + rb;
        #pragma unroll
        for (int ht = 0; ht < 2; ++ht){
          const uint32_t cb = W2To + (uint32_t)m2*2 + (uint32_t)(ht*16 + kg*4)*1040;
          uint16_t t0 = *(const uint16_t*)(smem + cb);
          uint16_t t1 = *(const uint16_t*)(smem + cb + 1040);
          uint16_t t2 = *(const uint16_t*)(smem + cb + 2080);
          uint16_t t3 = *(const uint16_t*)(smem + cb + 3120);
          uint2 u; u.x = (uint32_t)t0 | ((uint32_t)t1<<16);
                   u.y = (uint32_t)t2 | ((uint32_t)t3<<16);
          *(uint2*)(smem + W2Lo + m2*64 + ((((ht<<1)+(kg>>1)) ^ (m2&3))<<4) + ((kg&1)<<3)) = u;
        }
      }
      // b2 update (g_out^T row per thread)
      {
        uint4 gv = *(const uint4*)(smem + GOTo + tid*16);
        float gb2 = bf2f((uint16_t)gv.x) + bf2f((uint16_t)(gv.x>>16))
                  + bf2f((uint16_t)gv.y) + bf2f((uint16_t)(gv.y>>16))
                  + bf2f((uint16_t)gv.z) + bf2f((uint16_t)(gv.z>>16))
                  + bf2f((uint16_t)gv.w) + bf2f((uint16_t)(gv.w>>16));
        smb2 = e_t*smb2 - th_t*gb2;
        b2m = oma*b2m + smb2;
        b2L[tid] = b2m;
      }
      if (tid < 32){
        uint4 gv = *(const uint4*)(smem + GPTo + tid*16);
        float gb1 = bf2f((uint16_t)gv.x) + bf2f((uint16_t)(gv.x>>16))
                  + bf2f((uint16_t)gv.y) + bf2f((uint16_t)(gv.y>>16))
                  + bf2f((uint16_t)gv.z) + bf2f((uint16_t)(gv.z>>16))
                  + bf2f((uint16_t)gv.w) + bf2f((uint16_t)(gv.w>>16));
        smb1 = e_t*smb1 - th_t*gb1;
        b1m = oma*b1m + smb1;
        b1L[tid] = b1m;
      }
      // restage transposed K/V (after KT fragment reads above)
      *(uint4*)(smem + KTo + tid*16) = ktpf;
      *(uint4*)(smem + VTo + tid*16) = vtpf;
    }
    __syncthreads();
  }
}

// ---------------------------------------------------------------------------
extern "C" void kernel_launch(void* const* d_in, const int* in_sizes, int n_in,
                              void* d_out, int out_size, void* d_ws, size_t ws_size,
                              hipStream_t stream)
{
  const float* x   = (const float*)d_in[0];
  const float* Wk  = (const float*)d_in[1];
  const float* Wv  = (const float*)d_in[2];
  const float* Wq  = (const float*)d_in[3];
  const float* ckw = (const float*)d_in[4];
  const float* ckb = (const float*)d_in[5];
  const float* cvw = (const float*)d_in[6];
  const float* cvb = (const float*)d_in[7];
  const float* cqw = (const float*)d_in[8];
  const float* cqb = (const float*)d_in[9];
  const float* lng = (const float*)d_in[10];
  const float* lnb = (const float*)d_in[11];
  const float* W1g = (const float*)d_in[12];
  const float* b1g = (const float*)d_in[13];
  const float* W2g = (const float*)d_in[14];
  const float* b2g = (const float*)d_in[15];
  const float* aW1 = (const float*)d_in[16];
  const float* ab1 = (const float*)d_in[17];
  const float* aW2 = (const float*)d_in[18];
  const float* ab2 = (const float*)d_in[19];
  const float* tW1 = (const float*)d_in[20];
  const float* tb1 = (const float*)d_in[21];
  const float* tW2 = (const float*)d_in[22];
  const float* tb2 = (const float*)d_in[23];
  const float* eW1 = (const float*)d_in[24];
  const float* eb1 = (const float*)d_in[25];
  const float* eW2 = (const float*)d_in[26];
  const float* eb2 = (const float*)d_in[27];

  char* ws = (char*)d_ws;
  float* gates = (float*)ws;                       // 3*1024 f32
  uint16_t* preK  = (uint16_t*)(ws + 16384);       // 6 x 8MB bf16
  uint16_t* preV  = preK + 4194304;
  uint16_t* preQ  = preV + 4194304;
  uint16_t* postK = preQ + 4194304;
  uint16_t* postV = postK + 4194304;
  uint16_t* postQ = postV + 4194304;

  hipMemsetAsync(gates, 0, 3*1024*sizeof(float), stream);
  nltm_coeff<<<dim3(1024,3), 128, 0, stream>>>(x, aW1,ab1,aW2,ab2, tW1,tb1,tW2,tb2,
                                               eW1,eb1,eW2,eb2, gates);
  nltm_gemm<<<dim3(64,4,3), 256, 0, stream>>>(x, Wk, Wv, Wq, preK, preV, preQ);
  nltm_conv<<<dim3(8192,3), 512, 0, stream>>>(preK,preV,preQ, ckw,ckb,cvw,cvb,cqw,cqb,
                                              lng,lnb, postK,postV,postQ);
  nltm_scan<<<dim3(1), dim3(512), 0, stream>>>(W1g, b1g, W2g, b2g, gates,
                                               postK, postV, postQ, (float*)d_out);
}

// Round 4
// 10374.902 us; speedup vs baseline: 1.2851x; 1.0615x over previous
//
#include <hip/hip_runtime.h>
#include <hip/hip_bf16.h>
#include <cstdint>
#include <cstddef>

typedef __attribute__((ext_vector_type(8))) short bf16x8;
typedef __attribute__((ext_vector_type(4))) float f32x4;

#define DEV static __device__ __forceinline__

DEV float bf2f(uint16_t u){ union{uint32_t i; float f;} c; c.i = ((uint32_t)u) << 16; return c.f; }
DEV uint16_t f2bf(float f){ union{float f; uint32_t i;} c; c.f = f; uint32_t r = c.i + 0x7FFFu + ((c.i >> 16) & 1u); return (uint16_t)(r >> 16); }
DEV uint32_t cvtpk(float lo, float hi){
  uint32_t r;
  asm("v_cvt_pk_bf16_f32 %0, %1, %2" : "=v"(r) : "v"(lo), "v"(hi));
  return r;
}

DEV f32x4 mfma16(bf16x8 a, bf16x8 b, f32x4 c){
  return __builtin_amdgcn_mfma_f32_16x16x32_bf16(a, b, c, 0, 0, 0);
}

// ---------------------------------------------------------------------------
// Gate MLP: c[s] = mean_b sigmoid( silu(x[b,s,:]@W1^T + b1) @ W2^T + b2 )
// ---------------------------------------------------------------------------
__global__ __launch_bounds__(128) void nltm_coeff(
    const float* __restrict__ x,
    const float* __restrict__ aW1, const float* __restrict__ ab1,
    const float* __restrict__ aW2, const float* __restrict__ ab2,
    const float* __restrict__ tW1, const float* __restrict__ tb1,
    const float* __restrict__ tW2, const float* __restrict__ tb2,
    const float* __restrict__ eW1, const float* __restrict__ eb1,
    const float* __restrict__ eW2, const float* __restrict__ eb2,
    float* __restrict__ gates)
{
  const int s = blockIdx.x, z = blockIdx.y;
  const int b = threadIdx.x >> 4, ch = threadIdx.x & 15;
  const float* w1 = (z==0)?aW1:(z==1)?tW1:eW1;
  const float* c1 = (z==0)?ab1:(z==1)?tb1:eb1;
  const float* w2 = (z==0)?aW2:(z==1)?tW2:eW2;
  const float* c2 = (z==0)?ab2:(z==1)?tb2:eb2;
  const float4* xp = (const float4*)(x + ((size_t)(b << 10) + s)*512);
  const float4* wp = (const float4*)(w1 + ch*512);
  float dot = 0.f;
  #pragma unroll 4
  for (int i = 0; i < 128; ++i){
    float4 a = xp[i], c = wp[i];
    dot += a.x*c.x + a.y*c.y + a.z*c.z + a.w*c.w;
  }
  dot += c1[ch];
  const float sg = 1.f / (1.f + __expf(-dot));
  float v = dot * sg * w2[ch];
  v += __shfl_xor(v, 1, 64);
  v += __shfl_xor(v, 2, 64);
  v += __shfl_xor(v, 4, 64);
  v += __shfl_xor(v, 8, 64);
  if (ch == 0){
    const float cc = 1.f / (1.f + __expf(-(v + c2[0])));
    atomicAdd(gates + (z << 10) + s, cc * 0.125f);
  }
}

// ---------------------------------------------------------------------------
// f32 GEMM: pre[n,m] = sum_d x[n,d]*W[m,d]  (NT), bf16 output
// ---------------------------------------------------------------------------
__global__ __launch_bounds__(256) void nltm_gemm(
    const float* __restrict__ x, const float* __restrict__ Wk,
    const float* __restrict__ Wv, const float* __restrict__ Wq,
    uint16_t* __restrict__ preK, uint16_t* __restrict__ preV, uint16_t* __restrict__ preQ)
{
  __shared__ float As[16][132];
  __shared__ float Bs[16][132];
  const float* W = (blockIdx.z == 0) ? Wk : (blockIdx.z == 1) ? Wv : Wq;
  uint16_t* op  = (blockIdx.z == 0) ? preK : (blockIdx.z == 1) ? preV : preQ;
  const int tid = threadIdx.x;
  const int n0 = blockIdx.x << 7, m0 = blockIdx.y << 7;
  const int r = tid >> 1, cs = (tid & 1) << 3;
  const int ty = tid >> 4, tx = tid & 15;
  float acc[8][8];
  #pragma unroll
  for (int i = 0; i < 8; ++i)
    #pragma unroll
    for (int j = 0; j < 8; ++j) acc[i][j] = 0.f;

  for (int k0 = 0; k0 < 512; k0 += 16){
    float4 a0 = *(const float4*)(x + (size_t)(n0 + r)*512 + k0 + cs);
    float4 a1 = *(const float4*)(x + (size_t)(n0 + r)*512 + k0 + cs + 4);
    float4 b0 = *(const float4*)(W + (size_t)(m0 + r)*512 + k0 + cs);
    float4 b1 = *(const float4*)(W + (size_t)(m0 + r)*512 + k0 + cs + 4);
    __syncthreads();
    As[cs+0][r]=a0.x; As[cs+1][r]=a0.y; As[cs+2][r]=a0.z; As[cs+3][r]=a0.w;
    As[cs+4][r]=a1.x; As[cs+5][r]=a1.y; As[cs+6][r]=a1.z; As[cs+7][r]=a1.w;
    Bs[cs+0][r]=b0.x; Bs[cs+1][r]=b0.y; Bs[cs+2][r]=b0.z; Bs[cs+3][r]=b0.w;
    Bs[cs+4][r]=b1.x; Bs[cs+5][r]=b1.y; Bs[cs+6][r]=b1.z; Bs[cs+7][r]=b1.w;
    __syncthreads();
    #pragma unroll
    for (int kk = 0; kk < 16; ++kk){
      float4 av0 = *(const float4*)&As[kk][ty*8];
      float4 av1 = *(const float4*)&As[kk][ty*8+4];
      float4 bv0 = *(const float4*)&Bs[kk][tx*8];
      float4 bv1 = *(const float4*)&Bs[kk][tx*8+4];
      const float aa[8] = {av0.x,av0.y,av0.z,av0.w,av1.x,av1.y,av1.z,av1.w};
      const float bb[8] = {bv0.x,bv0.y,bv0.z,bv0.w,bv1.x,bv1.y,bv1.z,bv1.w};
      #pragma unroll
      for (int i = 0; i < 8; ++i)
        #pragma unroll
        for (int j = 0; j < 8; ++j)
          acc[i][j] = fmaf(aa[i], bb[j], acc[i][j]);
    }
  }
  #pragma unroll
  for (int i = 0; i < 8; ++i){
    const size_t n = (size_t)(n0 + ty*8 + i);
    uint4 v;
    v.x = (uint32_t)f2bf(acc[i][0]) | ((uint32_t)f2bf(acc[i][1]) << 16);
    v.y = (uint32_t)f2bf(acc[i][2]) | ((uint32_t)f2bf(acc[i][3]) << 16);
    v.z = (uint32_t)f2bf(acc[i][4]) | ((uint32_t)f2bf(acc[i][5]) << 16);
    v.w = (uint32_t)f2bf(acc[i][6]) | ((uint32_t)f2bf(acc[i][7]) << 16);
    *(uint4*)(op + n*512 + m0 + tx*8) = v;
  }
}

// ---------------------------------------------------------------------------
// depthwise conv (K=3, same) + optional LN.
// post  : [S][B][M] bf16 (natural for scan), nullable
// postT : [S][M][B] bf16 (transposed rows for scan KT/VT), nullable
// grid (8192), block 512; one launch per tensor
// ---------------------------------------------------------------------------
__global__ __launch_bounds__(512) void nltm_conv(
    const uint16_t* __restrict__ pre,
    const float* __restrict__ w, const float* __restrict__ wb,
    const float* __restrict__ lng, const float* __restrict__ lnb, const int doLN,
    uint16_t* __restrict__ post, uint16_t* __restrict__ postT)
{
  const int b = blockIdx.x >> 10, s = blockIdx.x & 1023;
  const int m = threadIdx.x;
  const size_t base = ((size_t)(b << 10) + s)*512 + m;
  const float xm = (s > 0)    ? bf2f(pre[base - 512]) : 0.f;
  const float x0 = bf2f(pre[base]);
  const float xp = (s < 1023) ? bf2f(pre[base + 512]) : 0.f;
  float y = fmaf(w[m*3], xm, fmaf(w[m*3+1], x0, fmaf(w[m*3+2], xp, wb[m])));
  if (doLN){
    __shared__ float red[2][8];
    float s1 = y, s2 = y*y;
    #pragma unroll
    for (int o = 32; o > 0; o >>= 1){
      s1 += __shfl_xor(s1, o, 64);
      s2 += __shfl_xor(s2, o, 64);
    }
    if ((threadIdx.x & 63) == 0){ red[0][threadIdx.x>>6] = s1; red[1][threadIdx.x>>6] = s2; }
    __syncthreads();
    float t1 = 0.f, t2 = 0.f;
    #pragma unroll
    for (int i = 0; i < 8; ++i){ t1 += red[0][i]; t2 += red[1][i]; }
    const float mean = t1 * (1.f/512.f);
    const float var  = t2 * (1.f/512.f) - mean*mean;
    y = (y - mean) * rsqrtf(var + 1e-5f) * lng[m] + lnb[m];
  }
  const uint16_t yb = f2bf(y);
  if (post)  post[((size_t)(s << 3) + b)*512 + m] = yb;
  if (postT) postT[(((size_t)s << 9) + m)*8 + b] = yb;
}

// ---------------------------------------------------------------------------
// Sequential scan: 1 block, 1024 threads (16 waves), 1024 steps.
// Stacked [q;k] 16-row MFMA operands; f32 masters in registers; packed LDS.
// LDS map (bytes):
//  W1L [32h][1040]      @0       33280   A: B-frag rows | D: uint2 writes
//  W2N [512m][64] swz   @33280   32768   B: B-frag rows | D: regen writes
//  W2T [32h][1040]      @66048   33280   C: B-frag rows | D: uint2 writes
//  QKL [16sb][1024] swz @99328   16384   rows 0-7 q, 8-15 k (B overwrites k
//                                        rows with g_out natural for C)
//  VT  [512m][16]       @115712  8192    B: uint2 reads | D restage
//  KT  [512m][16]       @123904  8192    D: A-frag rows | D restage
//  GOT [512m][16]       @132096  8192    B: uint2 writes | D: A-frag + b2
//  HQK [16sb][64]       @140288  1024    Ared scatter | B: A-frag rows
//  HKST[32h][16]        @141312  512     Ared uint2 | D: B-frag rows
//  SILP[32h][16]f32     @141824  2048    Ared float4 | Cred float4
//  GPT [32h][16]        @143872  512     Cred uint2 | D: B-frag + b1
//  SCR 16*64*16         @144384  16384   A-partials / C-partials
//  b1 @160768, b2 @160896 ; total 162944
// ---------------------------------------------------------------------------
__global__ __launch_bounds__(1024) void nltm_scan(
    const float* __restrict__ W1g, const float* __restrict__ b1g,
    const float* __restrict__ W2g, const float* __restrict__ b2g,
    const float* __restrict__ gates,
    const uint16_t* __restrict__ kN, const uint16_t* __restrict__ qN,
    const uint16_t* __restrict__ kT, const uint16_t* __restrict__ vT,
    float* __restrict__ out)
{
  constexpr uint32_t W1Lo=0, W2No=33280, W2To=66048, QKLo=99328, VTo=115712,
                     KTo=123904, GOTo=132096, HQKo=140288, HKSTo=141312,
                     SILPo=141824, GPTo=143872, SCRo=144384, B1o=160768, B2o=160896;
  __shared__ __align__(16) char smem[162944];
  const int tid = threadIdx.x;
  const int lane = tid & 63;
  const int wid = tid >> 6;        // 0..15
  const int rb = lane & 15;
  const int kg = lane >> 4;        // 0..3

  float* b1L = (float*)(smem + B1o);
  float* b2L = (float*)(smem + B2o);

  // ---- master state (f32, registers): wave wid owns m in [wid*32, wid*32+32) ----
  float w1m[4][4], sm1[4][4], w2a[4][4], sma[4][4];
  #pragma unroll
  for (int i = 0; i < 4; ++i){
    const int tt = i >> 1, ht = i & 1;
    const int mA = (wid*2 + tt)*16;
    #pragma unroll
    for (int j = 0; j < 4; ++j){
      const int h1 = ht*16 + rb, m1 = mA + kg*4 + j;
      w1m[i][j] = W1g[h1*512 + m1];  sm1[i][j] = 0.f;
      w2a[i][j] = W2g[m1*32 + h1];   sma[i][j] = 0.f;
    }
  }
  float b2m = (tid < 512) ? b2g[tid] : 0.f, smb2 = 0.f;
  float b1m = (tid < 32) ? b1g[tid] : 0.f, smb1 = 0.f;

  // ---- LDS weights init ----
  for (int idx = tid; idx < 16384; idx += 1024){
    const int h = idx >> 9, m = idx & 511;
    *(uint16_t*)(smem + W1Lo + h*1040 + m*2) = f2bf(W1g[idx]);          // idx=h*512+m
    const int m2 = idx >> 5, h2 = idx & 31;
    const float w2v = W2g[idx];                                          // idx=m2*32+h2
    *(uint16_t*)(smem + W2No + m2*64 + (((h2>>3)^(m2&3))<<4) + ((h2&7)<<1)) = f2bf(w2v);
    *(uint16_t*)(smem + W2To + h2*1040 + m2*2) = f2bf(w2v);
  }
  if (tid < 32) b1L[tid] = b1g[tid];
  if (tid < 512) b2L[tid] = b2g[tid];

  // ---- stage step 0 ----
  {
    const int b = tid >> 7, m4 = (tid & 127) << 2;
    const uint32_t swz = (((m4>>3) ^ (b&7))<<4) + ((m4&7)<<1);
    *(uint2*)(smem + QKLo + b*1024 + swz)       = *(const uint2*)(qN + tid*4);
    *(uint2*)(smem + QKLo + (8+b)*1024 + swz)   = *(const uint2*)(kN + tid*4);
    if (tid < 512) *(uint4*)(smem + KTo + tid*16) = *(const uint4*)(kT + tid*8);
    else           *(uint4*)(smem + VTo + (tid-512)*16) = *(const uint4*)(vT + (tid-512)*8);
  }
  __syncthreads();

  const f32x4 cz = {0.f, 0.f, 0.f, 0.f};
  const bf16x8 zf = {0,0,0,0,0,0,0,0};
  const int ht_ = wid & 1, ks_ = wid >> 1;

  for (int t = 0; t < 1024; ++t){
    // ---- prefetch next step (registers; consumed in phase D restage) ----
    const int tn = (t < 1023) ? (t + 1) : 1023;
    uint2 pfq = *(const uint2*)(qN + (size_t)tn*4096 + tid*4);
    uint2 pfk = *(const uint2*)(kN + (size_t)tn*4096 + tid*4);
    uint4 pf4;
    if (lane < 32) pf4 = *(const uint4*)(kT + (size_t)tn*4096 + (wid*32 + lane)*8);
    else           pf4 = *(const uint4*)(vT + (size_t)tn*4096 + (wid*32 + lane - 32)*8);
    const float a_t = gates[t], th_t = gates[1024 + t], e_t = gates[2048 + t];
    const float oma = 1.f - a_t;

    // ============ phase A: [hq;hk] = [q;k] @ W1^T  (16 waves: ht x ks8) ============
    {
      const uint32_t w1row = W1Lo + (uint32_t)(ht_*16 + rb)*1040;
      f32x4 acc = cz;
      #pragma unroll
      for (int u = 0; u < 2; ++u){
        const int c32 = ks_*2 + u;
        bf16x8 av = *(const bf16x8*)(smem + QKLo + rb*1024 + (((c32*4 + kg) ^ (rb&7)) << 4));
        bf16x8 bv = *(const bf16x8*)(smem + w1row + c32*64 + kg*16);
        acc = mfma16(av, bv, acc);
      }
      *(f32x4*)(smem + SCRo + ((wid*64 + lane) << 4)) = acc;
    }
    __syncthreads();

    // ============ Ared: reduce + silu/silu' (waves 0-1) ============
    if (wid < 2){
      const int ht = wid;
      f32x4 s = cz;
      #pragma unroll
      for (int ks = 0; ks < 8; ++ks)
        s += *(const f32x4*)(smem + SCRo + (((ks*2 + ht)*64 + lane) << 4));
      const int h = ht*16 + rb;
      const float b1v = b1L[h];
      float hs[4], sd[4];
      #pragma unroll
      for (int j = 0; j < 4; ++j){
        const float z = s[j] + b1v;
        const float sg = 1.f / (1.f + __expf(-z));
        hs[j] = z * sg;
        sd[j] = sg * (1.f + z * (1.f - sg));
      }
      #pragma unroll
      for (int j = 0; j < 4; ++j)
        *(uint16_t*)(smem + HQKo + (kg*4 + j)*64 + h*2) = f2bf(hs[j]);
      if (kg >= 2){
        uint2 hv; hv.x = cvtpk(hs[0], hs[1]); hv.y = cvtpk(hs[2], hs[3]);
        *(uint2*)(smem + HKSTo + h*16 + (kg-2)*8) = hv;
        f32x4 sv = {sd[0], sd[1], sd[2], sd[3]};
        *(f32x4*)(smem + SILPo + h*64 + (kg-2)*16) = sv;
      }
    }
    __syncthreads();

    // ============ phase B: [y;ck] = [hq;hk] @ W2^T ; y store; g_out ============
    {
      bf16x8 aF = *(const bf16x8*)(smem + HQKo + rb*64 + kg*16);
      #pragma unroll
      for (int u = 0; u < 2; ++u){
        const int mcol = (wid*2 + u)*16 + rb;
        bf16x8 bw = *(const bf16x8*)(smem + W2No + mcol*64 + ((kg ^ (mcol&3)) << 4));
        f32x4 c = mfma16(aF, bw, cz);
        const float b2v = b2L[mcol];
        if (kg < 2){
          #pragma unroll
          for (int j = 0; j < 4; ++j)
            out[(((size_t)(kg*4 + j) << 10) + t)*512 + mcol] = c[j] + b2v;
        } else {
          uint2 vt = *(const uint2*)(smem + VTo + mcol*16 + (kg-2)*8);
          float g0 = (c[0] + b2v - bf2f((uint16_t)vt.x))       * 4.8828125e-4f;
          float g1 = (c[1] + b2v - bf2f((uint16_t)(vt.x>>16))) * 4.8828125e-4f;
          float g2 = (c[2] + b2v - bf2f((uint16_t)vt.y))       * 4.8828125e-4f;
          float g3 = (c[3] + b2v - bf2f((uint16_t)(vt.y>>16))) * 4.8828125e-4f;
          uint2 gp; gp.x = cvtpk(g0, g1); gp.y = cvtpk(g2, g3);
          *(uint2*)(smem + GOTo + mcol*16 + (kg-2)*8) = gp;
          #pragma unroll
          for (int j = 0; j < 4; ++j){
            const int b = kg*4 + j - 8;
            const uint16_t gb = (uint16_t)((j & 1) ? ((j < 2 ? gp.x : gp.y) >> 16)
                                                   : (j < 2 ? gp.x : gp.y));
            *(uint16_t*)(smem + QKLo + (8+b)*1024 + (((mcol>>3) ^ (b&7)) << 4) + ((mcol&7) << 1)) = gb;
          }
        }
      }
    }
    __syncthreads();

    // ============ phase C: gpre_raw = g_out @ W2  (16 waves: ht x ks8) ============
    {
      const uint32_t w2row = W2To + (uint32_t)(ht_*16 + rb)*1040;
      f32x4 acc = cz;
      #pragma unroll
      for (int u = 0; u < 2; ++u){
        const int c32 = ks_*2 + u;
        bf16x8 av = (rb < 8) ? *(const bf16x8*)(smem + QKLo + (8+rb)*1024 + (((c32*4 + kg) ^ (rb&7)) << 4)) : zf;
        bf16x8 bv = *(const bf16x8*)(smem + w2row + c32*64 + kg*16);
        acc = mfma16(av, bv, acc);
      }
      *(f32x4*)(smem + SCRo + ((wid*64 + lane) << 4)) = acc;
    }
    __syncthreads();

    // ============ Cred: reduce + silu' -> GPT (waves 0-1, kg<2) ============
    if (wid < 2 && kg < 2){
      const int ht = wid;
      f32x4 s = cz;
      #pragma unroll
      for (int ks = 0; ks < 8; ++ks)
        s += *(const f32x4*)(smem + SCRo + (((ks*2 + ht)*64 + lane) << 4));
      const int h = ht*16 + rb;
      f32x4 sp = *(const f32x4*)(smem + SILPo + h*64 + kg*16);
      uint2 w; w.x = cvtpk(s[0]*sp[0], s[1]*sp[1]); w.y = cvtpk(s[2]*sp[2], s[3]*sp[3]);
      *(uint2*)(smem + GPTo + h*16 + kg*8) = w;
    }
    __syncthreads();

    // ============ phase D: grads (outer products), updates, restage ============
    {
      bf16x8 hkF[2], gpF[2];
      #pragma unroll
      for (int ht = 0; ht < 2; ++ht){
        const int r0 = ht*16 + rb;
        hkF[ht] = (kg == 0) ? *(const bf16x8*)(smem + HKSTo + r0*16) : zf;
        gpF[ht] = (kg == 0) ? *(const bf16x8*)(smem + GPTo  + r0*16) : zf;
      }
      #pragma unroll
      for (int tt = 0; tt < 2; ++tt){
        const int mA = (wid*2 + tt)*16;
        bf16x8 ktf = (kg == 0) ? *(const bf16x8*)(smem + KTo  + (mA + rb)*16) : zf;
        bf16x8 gof = (kg == 0) ? *(const bf16x8*)(smem + GOTo + (mA + rb)*16) : zf;
        #pragma unroll
        for (int ht = 0; ht < 2; ++ht){
          const int i = tt*2 + ht;
          f32x4 g1 = mfma16(ktf, gpF[ht], cz);   // GW1^T: (m=mA+kg*4+j, h=ht*16+rb)
          f32x4 g2 = mfma16(gof, hkF[ht], cz);   // GW2  : same mapping
          #pragma unroll
          for (int j = 0; j < 4; ++j){
            sm1[i][j] = e_t*sm1[i][j] - th_t*g1[j];
            w1m[i][j] = oma*w1m[i][j] + sm1[i][j];
            sma[i][j] = e_t*sma[i][j] - th_t*g2[j];
            w2a[i][j] = oma*w2a[i][j] + sma[i][j];
          }
          uint2 u1; u1.x = cvtpk(w1m[i][0], w1m[i][1]); u1.y = cvtpk(w1m[i][2], w1m[i][3]);
          *(uint2*)(smem + W1Lo + (ht*16 + rb)*1040 + (mA + kg*4)*2) = u1;
          uint2 u2; u2.x = cvtpk(w2a[i][0], w2a[i][1]); u2.y = cvtpk(w2a[i][2], w2a[i][3]);
          *(uint2*)(smem + W2To + (ht*16 + rb)*1040 + (mA + kg*4)*2) = u2;
        }
      }
      // W2N regen from own-wave W2T columns (bit-identical bf16)
      #pragma unroll
      for (int tt = 0; tt < 2; ++tt){
        const int m2 = (wid*2 + tt)*16 + rb;
        #pragma unroll
        for (int ht = 0; ht < 2; ++ht){
          const uint32_t cb = W2To + (uint32_t)m2*2 + (uint32_t)(ht*16 + kg*4)*1040;
          uint16_t t0 = *(const uint16_t*)(smem + cb);
          uint16_t t1 = *(const uint16_t*)(smem + cb + 1040);
          uint16_t t2 = *(const uint16_t*)(smem + cb + 2080);
          uint16_t t3 = *(const uint16_t*)(smem + cb + 3120);
          uint2 u; u.x = (uint32_t)t0 | ((uint32_t)t1 << 16);
                   u.y = (uint32_t)t2 | ((uint32_t)t3 << 16);
          *(uint2*)(smem + W2No + m2*64 + ((((ht<<1)+(kg>>1)) ^ (m2&3)) << 4) + ((kg&1) << 3)) = u;
        }
      }
      // bias updates
      if (tid < 512){
        uint4 gv = *(const uint4*)(smem + GOTo + tid*16);
        float gb2 = bf2f((uint16_t)gv.x) + bf2f((uint16_t)(gv.x>>16))
                  + bf2f((uint16_t)gv.y) + bf2f((uint16_t)(gv.y>>16))
                  + bf2f((uint16_t)gv.z) + bf2f((uint16_t)(gv.z>>16))
                  + bf2f((uint16_t)gv.w) + bf2f((uint16_t)(gv.w>>16));
        smb2 = e_t*smb2 - th_t*gb2;
        b2m = oma*b2m + smb2;
        b2L[tid] = b2m;
      }
      if (tid < 32){
        uint4 gv = *(const uint4*)(smem + GPTo + tid*16);
        float gb1 = bf2f((uint16_t)gv.x) + bf2f((uint16_t)(gv.x>>16))
                  + bf2f((uint16_t)gv.y) + bf2f((uint16_t)(gv.y>>16))
                  + bf2f((uint16_t)gv.z) + bf2f((uint16_t)(gv.z>>16))
                  + bf2f((uint16_t)gv.w) + bf2f((uint16_t)(gv.w>>16));
        smb1 = e_t*smb1 - th_t*gb1;
        b1m = oma*b1m + smb1;
        b1L[tid] = b1m;
      }
      // restage next step
      {
        const int b = tid >> 7, m4 = (tid & 127) << 2;
        const uint32_t swz = (((m4>>3) ^ (b&7))<<4) + ((m4&7)<<1);
        *(uint2*)(smem + QKLo + b*1024 + swz)     = pfq;
        *(uint2*)(smem + QKLo + (8+b)*1024 + swz) = pfk;
        if (lane < 32) *(uint4*)(smem + KTo + (wid*32 + lane)*16)      = pf4;
        else           *(uint4*)(smem + VTo + (wid*32 + lane - 32)*16) = pf4;
      }
    }
    __syncthreads();
  }
}

// ---------------------------------------------------------------------------
extern "C" void kernel_launch(void* const* d_in, const int* in_sizes, int n_in,
                              void* d_out, int out_size, void* d_ws, size_t ws_size,
                              hipStream_t stream)
{
  const float* x   = (const float*)d_in[0];
  const float* Wk  = (const float*)d_in[1];
  const float* Wv  = (const float*)d_in[2];
  const float* Wq  = (const float*)d_in[3];
  const float* ckw = (const float*)d_in[4];
  const float* ckb = (const float*)d_in[5];
  const float* cvw = (const float*)d_in[6];
  const float* cvb = (const float*)d_in[7];
  const float* cqw = (const float*)d_in[8];
  const float* cqb = (const float*)d_in[9];
  const float* lng = (const float*)d_in[10];
  const float* lnb = (const float*)d_in[11];
  const float* W1g = (const float*)d_in[12];
  const float* b1g = (const float*)d_in[13];
  const float* W2g = (const float*)d_in[14];
  const float* b2g = (const float*)d_in[15];
  const float* aW1 = (const float*)d_in[16];
  const float* ab1 = (const float*)d_in[17];
  const float* aW2 = (const float*)d_in[18];
  const float* ab2 = (const float*)d_in[19];
  const float* tW1 = (const float*)d_in[20];
  const float* tb1 = (const float*)d_in[21];
  const float* tW2 = (const float*)d_in[22];
  const float* tb2 = (const float*)d_in[23];
  const float* eW1 = (const float*)d_in[24];
  const float* eb1 = (const float*)d_in[25];
  const float* eW2 = (const float*)d_in[26];
  const float* eb2 = (const float*)d_in[27];

  char* ws = (char*)d_ws;
  float* gates = (float*)ws;                       // 3*1024 f32
  uint16_t* preK   = (uint16_t*)(ws + 16384);      // 6 x 8MB bf16
  uint16_t* preV   = preK + 4194304;               // reused as postKT after convV
  uint16_t* preQ   = preV + 4194304;
  uint16_t* postK  = preQ + 4194304;               // [S][B][M]
  uint16_t* postQ  = postK + 4194304;              // [S][B][M]
  uint16_t* postVT = postQ + 4194304;              // [S][M][B]
  uint16_t* postKT = preV;                         // [S][M][B] (overlay)

  hipMemsetAsync(gates, 0, 3*1024*sizeof(float), stream);
  nltm_coeff<<<dim3(1024,3), 128, 0, stream>>>(x, aW1,ab1,aW2,ab2, tW1,tb1,tW2,tb2,
                                               eW1,eb1,eW2,eb2, gates);
  nltm_gemm<<<dim3(64,4,3), 256, 0, stream>>>(x, Wk, Wv, Wq, preK, preV, preQ);
  // convV first (frees preV slot), then convK writes postKT into it
  nltm_conv<<<dim3(8192), 512, 0, stream>>>(preV, cvw, cvb, lng, lnb, 0, nullptr, postVT);
  nltm_conv<<<dim3(8192), 512, 0, stream>>>(preK, ckw, ckb, lng, lnb, 1, postK, postKT);
  nltm_conv<<<dim3(8192), 512, 0, stream>>>(preQ, cqw, cqb, lng, lnb, 1, postQ, nullptr);
  nltm_scan<<<dim3(1), dim3(1024), 0, stream>>>(W1g, b1g, W2g, b2g, gates,
                                                postK, postQ, postKT, postVT,
                                                (float*)d_out);
}